// Round 10
// baseline (262.119 us; speedup 1.0000x reference)
//
#include <hip/hip_runtime.h>
#include <hip/hip_bf16.h>

#define BATCH 2
#define SEQ   2048
#define EMBED 1024
#define HEADS 16
#define HDIM  64
#define NBH   (BATCH*HEADS)

typedef __attribute__((ext_vector_type(8))) short short8;
typedef __attribute__((ext_vector_type(4))) float floatx4;
typedef unsigned short u16;
typedef unsigned int   u32;

#define LOG2E 1.4426950408889634f

// async global->LDS, 16B per lane. LDS dest must be wave-uniform base + lane*16.
__device__ __forceinline__ void async_cp16(const void* g, void* l) {
  __builtin_amdgcn_global_load_lds((const __attribute__((address_space(1))) void*)g,
                                   (__attribute__((address_space(3))) void*)l,
                                   16, 0, 0);
}

__device__ __forceinline__ u16 f2b(float f) {  // f32 -> bf16 RNE
  union { float f; u32 u; } x; x.f = f;
  return (u16)((x.u + 0x7fffu + ((x.u >> 16) & 1u)) >> 16);
}
__device__ __forceinline__ float b2f(u16 b) {
  union { float f; u32 u; } x; x.u = ((u32)b) << 16;
  return x.f;
}
__device__ __forceinline__ u32 pk2(float a, float b) {  // packed bf16x2
  __hip_bfloat162 t = __float22bfloat162_rn(make_float2(a, b));
  return *reinterpret_cast<u32*>(&t);
}
__device__ __forceinline__ float fexp2(float x) {  // 2^x, single v_exp_f32
#if __has_builtin(__builtin_amdgcn_exp2f)
  return __builtin_amdgcn_exp2f(x);
#else
  return __expf(x * 0.6931471805599453f);
#endif
}

// ---------------------------------------------------------------------------
// f32 -> bf16 conversion of x, qkv_w, out_w (region bounds block-aligned).
// ---------------------------------------------------------------------------
__global__ __launch_bounds__(256)
void cvt_all(const float* __restrict__ x, const float* __restrict__ wqkv,
             const float* __restrict__ wo,
             u16* __restrict__ xb, u16* __restrict__ wqkvb, u16* __restrict__ wob) {
  const size_t t = (size_t)blockIdx.x * 256 + threadIdx.x;   // float4 index
  const float* src; u16* dst; size_t off;
  if (t < 1048576) { src = x; dst = xb; off = t; }
  else if (t < 1048576 + 786432) { src = wqkv; dst = wqkvb; off = t - 1048576; }
  else { src = wo; dst = wob; off = t - (1048576 + 786432); }
  float4 v = *(const float4*)(src + off * 4);
  ushort4 o;
  o.x = f2b(v.x); o.y = f2b(v.y); o.z = f2b(v.z); o.w = f2b(v.w);
  *(ushort4*)(dst + off * 4) = o;
}

// ---------------------------------------------------------------------------
// Fused QKV GEMM, BK=64 (unchanged from r8). Grid (24,32)=768 = 3/CU.
// ---------------------------------------------------------------------------
__global__ __launch_bounds__(256, 3)
void qkv_gemm(const u16* __restrict__ X, const u16* __restrict__ W,
              u16* __restrict__ q_ws, u16* __restrict__ k_ws,
              u16* __restrict__ vT_ws) {
  __shared__ u16 As[8][128][8];   // 16 KB: k-chunks 0..7 (BK=64)
  __shared__ u16 Bs[8][128][8];   // 16 KB
  const int tid  = threadIdx.x;
  const int lane = tid & 63, wv = tid >> 6;
  const int l15  = lane & 15, quad = lane >> 4;
  const int wm = (wv >> 1) << 6, wn = (wv & 1) << 6;
  const int m0 = blockIdx.y << 7, n0 = blockIdx.x << 7;
  const bool vpath = (n0 >= 2048);

  floatx4 acc[4][4];
#pragma unroll
  for (int i = 0; i < 4; ++i)
#pragma unroll
    for (int j = 0; j < 4; ++j) acc[i][j] = {0.f, 0.f, 0.f, 0.f};

  if (!vpath) {
    for (int k0 = 0; k0 < EMBED; k0 += 64) {
      __syncthreads();
#pragma unroll
      for (int i = 0; i < 4; ++i) {
        int c = tid + (i << 8);
        int kb = c >> 7, row = c & 127;
        async_cp16(X + (size_t)(m0 + row) * EMBED + k0 + kb * 8, &As[kb][row][0]);
        async_cp16(W + (size_t)(n0 + row) * EMBED + k0 + kb * 8, &Bs[kb][row][0]);
      }
      __syncthreads();

#pragma unroll
      for (int ks = 0; ks < 2; ++ks) {
        short8 af[4], bf[4];
#pragma unroll
        for (int t = 0; t < 4; ++t) {
          af[t] = *(const short8*)&As[ks * 4 + quad][wm + t * 16 + l15][0];
          bf[t] = *(const short8*)&Bs[ks * 4 + quad][wn + t * 16 + l15][0];
        }
#pragma unroll
        for (int i = 0; i < 4; ++i)
#pragma unroll
          for (int j = 0; j < 4; ++j)
            acc[i][j] = __builtin_amdgcn_mfma_f32_16x16x32_bf16(bf[j], af[i], acc[i][j], 0, 0, 0);
      }
    }

#pragma unroll
    for (int i = 0; i < 4; ++i) {
      int mg = m0 + wm + i * 16 + l15;
      int b = mg >> 11, s = mg & 2047;
#pragma unroll
      for (int j = 0; j < 4; ++j) {
        int col0 = n0 + wn + j * 16 + (quad << 2);
        int c = col0 >> 10, hd = col0 & 1023;
        int h = hd >> 6, d0 = hd & 63;
        u16* dst = c ? k_ws : q_ws;
        uint2 w;
        w.x = pk2(acc[i][j][0], acc[i][j][1]);
        w.y = pk2(acc[i][j][2], acc[i][j][3]);
        *(uint2*)(dst + (((size_t)(b * HEADS + h)) * SEQ + s) * HDIM + d0) = w;
      }
    }
  } else {
    for (int k0 = 0; k0 < EMBED; k0 += 64) {
      __syncthreads();
#pragma unroll
      for (int i = 0; i < 4; ++i) {
        int c = tid + (i << 8);
        int kb = c >> 7, row = c & 127;
        async_cp16(X + (size_t)(m0 + row) * EMBED + k0 + kb * 8, &As[kb][row][0]);
        async_cp16(W + (size_t)(n0 + row) * EMBED + k0 + kb * 8, &Bs[kb][row][0]);
      }
      __syncthreads();

#pragma unroll
      for (int ks = 0; ks < 2; ++ks) {
        short8 af[4], bf[4];
#pragma unroll
        for (int t = 0; t < 4; ++t) {
          af[t] = *(const short8*)&As[ks * 4 + quad][wm + t * 16 + l15][0];
          bf[t] = *(const short8*)&Bs[ks * 4 + quad][wn + t * 16 + l15][0];
        }
#pragma unroll
        for (int i = 0; i < 4; ++i)
#pragma unroll
          for (int j = 0; j < 4; ++j)
            acc[i][j] = __builtin_amdgcn_mfma_f32_16x16x32_bf16(af[i], bf[j], acc[i][j], 0, 0, 0);
      }
    }

#pragma unroll
    for (int i = 0; i < 4; ++i) {
      int mg0 = m0 + wm + i * 16 + (quad << 2);
      int b = mg0 >> 11, s0 = mg0 & 2047;
#pragma unroll
      for (int j = 0; j < 4; ++j) {
        int col = n0 + wn + j * 16 + l15;
        int hd = col & 1023;
        int h = hd >> 6, d = hd & 63;
        uint2 w;
        w.x = pk2(acc[i][j][0], acc[i][j][1]);
        w.y = pk2(acc[i][j][2], acc[i][j][3]);
        *(uint2*)(vT_ws + (((size_t)(b * HEADS + h)) * HDIM + d) * SEQ + s0) = w;
      }
    }
  }
}

// ---------------------------------------------------------------------------
// Flash attention v7 (r9 design, workspace-safe): split-KV x2 with fixed-max
// softmax (partials exact). Opart0 aliases ao (combine normalizes in place),
// Opart1 aliases xb (dead after qkv_gemm), lpart aliases wqkvb (dead too).
// Grid (32,32,2) = 2048 blocks; LDS 25.6KB -> 6 blocks/CU = 24 waves/CU.
// ---------------------------------------------------------------------------
__global__ __launch_bounds__(256, 6)
void attn_part(const u16* __restrict__ q_ws, const u16* __restrict__ k_ws,
               const u16* __restrict__ vT_ws, const int* __restrict__ mask,
               u16* __restrict__ Opart0, u16* __restrict__ Opart1,
               float* __restrict__ lpart) {
  __shared__ u16 Ks[8][64][8];     // 8 KB [d/8][t][8]
  __shared__ u16 Vt[8][64][8];     // 8 KB [t/8][d][8]
  __shared__ u16 Ps[4][16][68];    // 8.5 KB P^T [wave][q][t+pad4]
  __shared__ float msk[64];

  const int tid  = threadIdx.x;
  const int lane = tid & 63, wv = tid >> 6;
  const int l15  = lane & 15, quad = lane >> 4;
  const int bh = blockIdx.y;
  const int b  = bh >> 4, h = bh & 15;
  const int z  = blockIdx.z;
  const int qrw = (blockIdx.x << 6) + (wv << 4);
  const int tbase = z << 10;                     // this block's KV half

  const u16* Qb  = q_ws  + (size_t)bh * SEQ * HDIM;
  const u16* Kb  = k_ws  + (size_t)bh * SEQ * HDIM;
  const u16* VbT = vT_ws + (size_t)bh * HDIM * SEQ;

  // Q B-frags: B[k=d=quad*8+j][n=q=l15], pre-scaled by 1/8 (exact in bf16)
  short8 qf[2];
#pragma unroll
  for (int s = 0; s < 2; ++s) {
    short8 v = *(const short8*)(Qb + (size_t)(qrw + l15) * HDIM + s * 32 + quad * 8);
#pragma unroll
    for (int e = 0; e < 8; ++e) {
      union { float f; u32 u; } x;
      x.u = ((u32)(u16)v[e]) << 16;
      x.f *= 0.125f;
      v[e] = (short)(x.u >> 16);
    }
    qf[s] = v;
  }

  float l_acc = 0.f;
  floatx4 O[4];
#pragma unroll
  for (int dt = 0; dt < 4; ++dt) O[dt] = {0.f, 0.f, 0.f, 0.f};

  for (int ti = 0; ti < 16; ++ti) {
    const int t0 = tbase + (ti << 6);
    __syncthreads();
#pragma unroll
    for (int i = 0; i < 2; ++i) {
      int c = tid + (i << 8);
      int kb = c >> 6, r = c & 63;
      async_cp16(Kb + (size_t)(t0 + r) * HDIM + kb * 8, &Ks[kb][r][0]);
      async_cp16(VbT + (size_t)r * SEQ + t0 + kb * 8, &Vt[kb][r][0]);
    }
    // mask constant carries the fixed shift: p = 2^(s*log2e + msk)
    if (tid < 64) msk[tid] = mask[b * SEQ + t0 + tid] ? -12.0f : -1e30f;
    __syncthreads();

    // S^T = K·(Q/8)^T : D[t=nt*16+quad*4+r][q=l15]
    floatx4 sc[4];
#pragma unroll
    for (int nt = 0; nt < 4; ++nt) {
      sc[nt] = {0.f, 0.f, 0.f, 0.f};
#pragma unroll
      for (int s = 0; s < 2; ++s) {
        short8 kf = *(const short8*)&Ks[s * 4 + quad][nt * 16 + l15][0];
        sc[nt] = __builtin_amdgcn_mfma_f32_16x16x32_bf16(kf, qf[s], sc[nt], 0, 0, 0);
      }
    }

    // p = 2^(s*log2e + msk); in-lane l accumulation; packed bf16 P^T store
#pragma unroll
    for (int nt = 0; nt < 4; ++nt) {
      const float4 m4 = *(const float4*)&msk[nt * 16 + quad * 4];
      float pv[4];
#pragma unroll
      for (int r = 0; r < 4; ++r) {
        pv[r] = fexp2(fmaf(sc[nt][r], LOG2E, (&m4.x)[r]));
        l_acc += pv[r];
      }
      uint2 w;
      w.x = pk2(pv[0], pv[1]); w.y = pk2(pv[2], pv[3]);
      *(uint2*)&Ps[wv][l15][nt * 16 + (quad << 2)] = w;
    }

    // O^T += V^T·P^T : A = Vt (m=d), B = Ps (n=q); wave-local, no barrier
#pragma unroll
    for (int tch = 0; tch < 2; ++tch) {
      short8 pf = *(const short8*)&Ps[wv][l15][tch * 32 + quad * 8];
#pragma unroll
      for (int dt = 0; dt < 4; ++dt) {
        short8 vf = *(const short8*)&Vt[tch * 4 + quad][dt * 16 + l15][0];
        O[dt] = __builtin_amdgcn_mfma_f32_16x16x32_bf16(vf, pf, O[dt], 0, 0, 0);
      }
    }
  }

  // partial l: cross-quad sum, one writer per q
  l_acc += __shfl_xor(l_acc, 16);
  l_acc += __shfl_xor(l_acc, 32);
  if (quad == 0)
    lpart[((size_t)z << 16) + bh * SEQ + qrw + l15] = l_acc;

  // partial O (unnormalized) in ao-layout bf16
  u16* Op = z ? Opart1 : Opart0;
  const size_t rowbase = ((size_t)(b * SEQ + qrw + l15)) * EMBED + h * 64;
#pragma unroll
  for (int dt = 0; dt < 4; ++dt) {
    uint2 w;
    w.x = pk2(O[dt][0], O[dt][1]);
    w.y = pk2(O[dt][2], O[dt][3]);
    *(uint2*)(Op + rowbase + dt * 16 + (quad << 2)) = w;
  }
}

// ---------------------------------------------------------------------------
// Combine: ao = (O0 + O1) / (l0 + l1). ao aliases Opart0 (in-place, each
// thread owns its elements). 4 elems/thread.
// ---------------------------------------------------------------------------
__global__ __launch_bounds__(256)
void attn_combine(u16* __restrict__ Opart0, const u16* __restrict__ Opart1,
                  const float* __restrict__ lpart) {
  const size_t idx4 = (size_t)blockIdx.x * 256 + threadIdx.x;  // uint2 index
  const size_t i = idx4 << 2;                                  // element index
  const int b = (int)(i >> 21), s = (int)((i >> 10) & 2047), h = (int)((i >> 6) & 15);
  const size_t lidx = (size_t)((b << 4) | h) * SEQ + s;
  const float inv = 1.f / (lpart[lidx] + lpart[lidx + (1u << 16)]);

  uint2 a = *(const uint2*)(Opart0 + i);
  uint2 c = *(const uint2*)(Opart1 + i);
  float o0 = b2f((u16)(a.x)) + b2f((u16)(c.x));
  float o1 = b2f((u16)(a.x >> 16)) + b2f((u16)(c.x >> 16));
  float o2 = b2f((u16)(a.y)) + b2f((u16)(c.y));
  float o3 = b2f((u16)(a.y >> 16)) + b2f((u16)(c.y >> 16));
  uint2 w;
  w.x = pk2(o0 * inv, o1 * inv);
  w.y = pk2(o2 * inv, o3 * inv);
  *(uint2*)(Opart0 + i) = w;
}

// ---------------------------------------------------------------------------
// Output projection (r6/r8 config): 128x64 tiles, grid (16,32)=512 = 2/CU.
// ---------------------------------------------------------------------------
__global__ __launch_bounds__(256, 2)
void proj_gemm(const u16* __restrict__ A, const u16* __restrict__ W,
               const float* __restrict__ bias, float* __restrict__ out) {
  __shared__ u16 As[4][128][8];
  __shared__ u16 Bs[4][64][8];
  const int tid  = threadIdx.x;
  const int lane = tid & 63, wv = tid >> 6;
  const int l15  = lane & 15, quad = lane >> 4;
  const int wm = (wv >> 1) << 6, wn = (wv & 1) << 5;
  const int m0 = blockIdx.y << 7, n0 = blockIdx.x << 6;

  floatx4 acc[4][2];
#pragma unroll
  for (int i = 0; i < 4; ++i)
#pragma unroll
    for (int j = 0; j < 2; ++j) acc[i][j] = {0.f, 0.f, 0.f, 0.f};

  for (int k0 = 0; k0 < EMBED; k0 += 32) {
    __syncthreads();
#pragma unroll
    for (int i = 0; i < 2; ++i) {
      int c = tid + (i << 8);
      int kb = c >> 7, row = c & 127;
      async_cp16(A + (size_t)(m0 + row) * EMBED + k0 + kb * 8, &As[kb][row][0]);
    }
    {
      int kb = tid >> 6, row = tid & 63;
      async_cp16(W + (size_t)(n0 + row) * EMBED + k0 + kb * 8, &Bs[kb][row][0]);
    }
    __syncthreads();

    short8 af[4], bf[2];
#pragma unroll
    for (int t = 0; t < 4; ++t)
      af[t] = *(const short8*)&As[quad][wm + t * 16 + l15][0];
#pragma unroll
    for (int t = 0; t < 2; ++t)
      bf[t] = *(const short8*)&Bs[quad][wn + t * 16 + l15][0];
#pragma unroll
    for (int i = 0; i < 4; ++i)
#pragma unroll
      for (int j = 0; j < 2; ++j)
        acc[i][j] = __builtin_amdgcn_mfma_f32_16x16x32_bf16(bf[j], af[i], acc[i][j], 0, 0, 0);
  }

#pragma unroll
  for (int i = 0; i < 4; ++i) {
    int m = m0 + wm + i * 16 + l15;
#pragma unroll
    for (int j = 0; j < 2; ++j) {
      int col0 = n0 + wn + j * 16 + (quad << 2);
      float4 bv = *(const float4*)(bias + col0);
      float4 o;
      o.x = acc[i][j][0] + bv.x;
      o.y = acc[i][j][1] + bv.y;
      o.z = acc[i][j][2] + bv.z;
      o.w = acc[i][j][3] + bv.w;
      *(float4*)(out + (size_t)m * EMBED + col0) = o;
    }
  }
}

extern "C" void kernel_launch(void* const* d_in, const int* in_sizes, int n_in,
                              void* d_out, int out_size, void* d_ws, size_t ws_size,
                              hipStream_t stream) {
  const float* x     = (const float*)d_in[0];
  const int*   mask  = (const int*)d_in[1];
  const float* qkv_w = (const float*)d_in[2];
  const float* out_w = (const float*)d_in[3];
  const float* out_b = (const float*)d_in[4];
  float* out = (float*)d_out;

  // 48 MiB workspace layout (identical footprint to the passing r8):
  //   xb     [4.19M u16]  x bf16        -> dead after qkv_gemm -> Opart1
  //   wqkvb  [3.15M u16]  qkv_w bf16    -> dead after qkv_gemm -> lpart
  //   wob    [1.05M u16]  out_w bf16    (live until proj)
  //   q_ws/k_ws/vT_ws [3 x 4.19M u16]   (live until attn_part)
  //   ao     [4.19M u16]  = Opart0, normalized in place by attn_combine
  const size_t per = (size_t)NBH * SEQ * HDIM;      // 4,194,304 elems
  u16* xb    = (u16*)d_ws;                          // 4,194,304
  u16* wqkvb = xb + 4194304;                        // 3,145,728
  u16* wob   = wqkvb + 3145728;                     // 1,048,576
  u16* q_ws  = wob + 1048576;
  u16* k_ws  = q_ws + per;
  u16* vT_ws = k_ws + per;                          // V^T [bh][d][s]
  u16* ao    = vT_ws + per;                         // 4096 x 1024 bf16
  u16* Opart0 = ao;                                 // alias: partial O (z=0)
  u16* Opart1 = xb;                                 // alias: partial O (z=1)
  float* lpart = (float*)wqkvb;                     // alias: 2 x 65536 f32

  cvt_all<<<8192, 256, 0, stream>>>(x, qkv_w, out_w, xb, wqkvb, wob);
  qkv_gemm<<<dim3(24, 32), 256, 0, stream>>>(xb, wqkvb, q_ws, k_ws, vT_ws);
  attn_part<<<dim3(SEQ / 64, NBH, 2), 256, 0, stream>>>(q_ws, k_ws, vT_ws, mask, Opart0, Opart1, lpart);
  attn_combine<<<4096, 256, 0, stream>>>(Opart0, Opart1, lpart);
  proj_gemm<<<dim3(16, 32), 256, 0, stream>>>(ao, wob, out_b, out);
}